// Round 2
// baseline (956.009 us; speedup 1.0000x reference)
//
#include <hip/hip_runtime.h>
#include <stdint.h>

typedef unsigned int u32;
typedef unsigned short u16;

#define DI __device__ __forceinline__

DI float bf2f(u16 u) { union { u32 i; float f; } v; v.i = ((u32)u) << 16; return v.f; }
DI u16 f2bf(float f) {
    union { u32 i; float f; } v; v.f = f;
    u32 u = v.i;
    u32 r = (u + 0x7fffu + ((u >> 16) & 1u)) >> 16;
    return (u16)r;
}
DI float2 unpack2(u32 x) { return make_float2(bf2f((u16)(x & 0xffffu)), bf2f((u16)(x >> 16))); }
DI u32 pack2(float a, float b) { return (u32)f2bf(a) | ((u32)f2bf(b) << 16); }

// ---------------- convert x (f32) -> bf16 ----------------

__global__ void cvt_bf16(const float* __restrict__ X, u16* __restrict__ Xb, int total4) {
    int i = blockIdx.x * blockDim.x + threadIdx.x;
    if (i >= total4) return;
    float4 v = ((const float4*)X)[i];
    ushort4 o;
    o.x = f2bf(v.x); o.y = f2bf(v.y); o.z = f2bf(v.z); o.w = f2bf(v.w);
    ((ushort4*)Xb)[i] = o;
}

// ---------------- CSR build ----------------

__global__ void edge_stats(const int* __restrict__ ei, const float* __restrict__ mask,
                           int* __restrict__ cnt, int* __restrict__ cntm, int E) {
    int e = blockIdx.x * blockDim.x + threadIdx.x;
    if (e >= E) return;
    int c = ei[e];          // src (col)
    int r = ei[E + e];      // dst (row)
    if (r != c) {
        atomicAdd(&cnt[r], 1);
        if (mask[c] != 0.f) atomicAdd(&cntm[r], 1);
    }
}

#define SCAN_B 1024
__global__ __launch_bounds__(1024) void scanA(const int* __restrict__ cnt, int* __restrict__ rowptr,
                                              int* __restrict__ blocksum, int n) {
    __shared__ int s[SCAN_B];
    int t = threadIdx.x;
    int i = blockIdx.x * SCAN_B + t;
    int v = (i < n) ? cnt[i] : 0;
    s[t] = v; __syncthreads();
    for (int off = 1; off < SCAN_B; off <<= 1) {
        int tmp = (t >= off) ? s[t - off] : 0;
        __syncthreads();
        s[t] += tmp;
        __syncthreads();
    }
    if (i < n) rowptr[i] = s[t] - v;   // local exclusive
    if (t == SCAN_B - 1) blocksum[blockIdx.x] = s[t];
}

__global__ void scanB(const int* __restrict__ blocksum, int* __restrict__ blockoff,
                      int nblk, int* __restrict__ rowptr, int n) {
    __shared__ int s[128];
    int t = threadIdx.x;
    int v = (t < nblk) ? blocksum[t] : 0;
    s[t] = v; __syncthreads();
    for (int off = 1; off < 128; off <<= 1) {
        int tmp = (t >= off) ? s[t - off] : 0;
        __syncthreads();
        s[t] += tmp;
        __syncthreads();
    }
    if (t < nblk) blockoff[t] = s[t] - v;
    if (t == 127) rowptr[n] = s[127];
}

__global__ void scanC(int* __restrict__ rowptr, int* __restrict__ cursor,
                      const int* __restrict__ blockoff, int n) {
    int i = blockIdx.x * blockDim.x + threadIdx.x;
    if (i < n) {
        int v = rowptr[i] + blockoff[i >> 10];
        rowptr[i] = v;
        cursor[i] = v;
    }
}

__global__ void scatter_edges(const int* __restrict__ ei, const float* __restrict__ mask,
                              int* __restrict__ cursor, int* __restrict__ sorted, int E) {
    int e = blockIdx.x * blockDim.x + threadIdx.x;
    if (e >= E) return;
    int c = ei[e];
    int r = ei[E + e];
    if (r != c) {
        int pos = atomicAdd(&cursor[r], 1);
        sorted[pos] = c | ((mask[c] != 0.f) ? (int)0x80000000 : 0);
    }
}

// ---------------- per-node normalization ----------------

__global__ void norm_kernel(const int* __restrict__ cnt, const int* __restrict__ cntm,
                            const float* __restrict__ mask,
                            float* __restrict__ dinvL, float* __restrict__ dinvH,
                            float* __restrict__ dinvLL, float* __restrict__ dinvHH,
                            float* __restrict__ diagL, float* __restrict__ diagH,
                            float* __restrict__ diagLL, float* __restrict__ diagHH, int n) {
    int i = blockIdx.x * blockDim.x + threadIdx.x;
    if (i >= n) return;
    float c = (float)cnt[i];
    float cm = (float)cntm[i];
    bool mi = mask[i] != 0.f;
    float degL = (mi ? c : 0.f) + 1.f;
    float degH = (mi ? 0.f : c) + 1.f;
    float degLL = cm + 1.f;
    float degHH = (c - cm) + 1.f;
    dinvL[i] = rsqrtf(degL);   diagL[i] = 1.f / degL;
    dinvH[i] = rsqrtf(degH);   diagH[i] = 1.f / degH;
    dinvLL[i] = rsqrtf(degLL); diagLL[i] = 1.f / degLL;
    dinvHH[i] = rsqrtf(degHH); diagHH[i] = 1.f / degHH;
}

// ---------------- SpMM layer 1 (by-row masks: one gather feeds one path, other path = copy) ----------------

__global__ __launch_bounds__(256) void spmm1(const u16* __restrict__ X,
                                             const int* __restrict__ rowptr, const int* __restrict__ sorted,
                                             const float* __restrict__ mask,
                                             const float* __restrict__ dinvL, const float* __restrict__ dinvH,
                                             const float* __restrict__ diagL, const float* __restrict__ diagH,
                                             u16* __restrict__ Yl, u16* __restrict__ Yh, int n) {
    int r = blockIdx.x * 4 + (threadIdx.x >> 6);
    if (r >= n) return;
    int lane = threadIdx.x & 63;
    bool mi = mask[r] != 0.f;
    const float* dinvA = mi ? dinvL : dinvH;
    float diag = mi ? diagL[r] : diagH[r];
    float da = dinvA[r];
    const u32* Xr = (const u32*)X;
    u32 xv = Xr[(size_t)r * 64 + lane];
    float2 xf = unpack2(xv);
    float a0 = diag * xf.x, a1 = diag * xf.y;
    int e0 = rowptr[r], e1 = rowptr[r + 1];
    for (int e = e0; e < e1; e++) {
        int p = sorted[e];
        int c = p & 0x7FFFFFFF;
        float w = da * dinvA[c];
        float2 xc = unpack2(Xr[(size_t)c * 64 + lane]);
        a0 += w * xc.x;
        a1 += w * xc.y;
    }
    u32* Ya = (u32*)(mi ? Yl : Yh);
    u32* Yc = (u32*)(mi ? Yh : Yl);
    Ya[(size_t)r * 64 + lane] = pack2(a0, a1);
    Yc[(size_t)r * 64 + lane] = xv;   // deg=1, diag=1 -> exact copy
}

// ---------------- SpMM layer 2 (by-col masks: each edge feeds exactly one path) ----------------

__global__ __launch_bounds__(256) void spmm2(const u16* __restrict__ XL, const u16* __restrict__ XH,
                                             const int* __restrict__ rowptr, const int* __restrict__ sorted,
                                             const float* __restrict__ dinvLL, const float* __restrict__ dinvHH,
                                             const float* __restrict__ diagLL, const float* __restrict__ diagHH,
                                             u16* __restrict__ Zl, u16* __restrict__ Zh, int n) {
    int r = blockIdx.x * 4 + (threadIdx.x >> 6);
    if (r >= n) return;
    int lane = threadIdx.x & 63;
    const u32* XLr = (const u32*)XL;
    const u32* XHr = (const u32*)XH;
    u32 xlv = XLr[(size_t)r * 64 + lane];
    u32 xhv = XHr[(size_t)r * 64 + lane];
    float2 xl = unpack2(xlv), xh = unpack2(xhv);
    float dll = dinvLL[r], dhh = dinvHH[r];
    float cl = diagLL[r], ch = diagHH[r];
    float l0 = cl * xl.x, l1 = cl * xl.y;
    float h0 = ch * xh.x, h1 = ch * xh.y;
    int e0 = rowptr[r], e1 = rowptr[r + 1];
    for (int e = e0; e < e1; e++) {
        int p = sorted[e];
        int c = p & 0x7FFFFFFF;
        if (p < 0) {  // source masked (low path)
            float w = dll * dinvLL[c];
            float2 v = unpack2(XLr[(size_t)c * 64 + lane]);
            l0 += w * v.x; l1 += w * v.y;
        } else {      // high path
            float w = dhh * dinvHH[c];
            float2 v = unpack2(XHr[(size_t)c * 64 + lane]);
            h0 += w * v.x; h1 += w * v.y;
        }
    }
    ((u32*)Zl)[(size_t)r * 64 + lane] = pack2(l0, l1);
    ((u32*)Zh)[(size_t)r * 64 + lane] = pack2(h0, h1);
}

// ---------------- weight transpose f32 -> bf16 (Bt[n][k] contiguous in k) ----------------

__global__ void transposeW(const float* __restrict__ W1L, const float* __restrict__ W1H,
                           const float* __restrict__ W2L, const float* __restrict__ W2H,
                           const float* __restrict__ WX, u16* __restrict__ Bt) {
    int w = blockIdx.x >> 6;                         // which weight
    int idx = (blockIdx.x & 63) * 256 + threadIdx.x; // 0..16383
    const float* src = (w == 0) ? W1L : (w == 1) ? W1H : (w == 2) ? W2L : (w == 3) ? W2H : WX;
    int k = idx >> 7, nn = idx & 127;
    Bt[(size_t)w * 16384 + (size_t)nn * 128 + k] = f2bf(src[idx]);
}

// ---------------- MFMA GEMM: C[M,128] = op(A[M,128] @ B[128,128]) ----------------

typedef __attribute__((ext_vector_type(8))) short bf16x8;
typedef __attribute__((ext_vector_type(4))) float f32x4;

__global__ __launch_bounds__(256) void gemm128(const u16* __restrict__ A, const u16* __restrict__ Bt,
                                               u16* __restrict__ C, int M, int do_relu) {
    int wave = threadIdx.x >> 6;
    int lane = threadIdx.x & 63;
    int quad = lane >> 4;
    int l16 = lane & 15;
    int m0 = blockIdx.x * 64 + wave * 16 + l16;   // A-fragment row

    bf16x8 afrag[4];
    bf16x8 zero = {0, 0, 0, 0, 0, 0, 0, 0};
    if (m0 < M) {
        const u16* arow = A + (size_t)m0 * 128 + quad * 8;
#pragma unroll
        for (int kb = 0; kb < 4; kb++)
            afrag[kb] = *(const bf16x8*)(arow + kb * 32);
    } else {
#pragma unroll
        for (int kb = 0; kb < 4; kb++) afrag[kb] = zero;
    }

    f32x4 acc[8];
#pragma unroll
    for (int nt = 0; nt < 8; nt++) acc[nt] = f32x4{0.f, 0.f, 0.f, 0.f};

#pragma unroll
    for (int nt = 0; nt < 8; nt++) {
        const u16* brow = Bt + (size_t)(nt * 16 + l16) * 128 + quad * 8;
#pragma unroll
        for (int kb = 0; kb < 4; kb++) {
            bf16x8 b = *(const bf16x8*)(brow + kb * 32);
            acc[nt] = __builtin_amdgcn_mfma_f32_16x16x32_bf16(afrag[kb], b, acc[nt], 0, 0, 0);
        }
    }

    int rbase = blockIdx.x * 64 + wave * 16 + quad * 4;
#pragma unroll
    for (int nt = 0; nt < 8; nt++) {
#pragma unroll
        for (int rr = 0; rr < 4; rr++) {
            int row = rbase + rr;
            if (row < M) {
                float v = acc[nt][rr];
                if (do_relu) v = v > 0.f ? v : 0.f;
                C[(size_t)row * 128 + nt * 16 + l16] = f2bf(v);
            }
        }
    }
}

// ---------------- fused gate + [N,128]x[128,10] epilogue (f32 out) ----------------

__global__ __launch_bounds__(256) void final_k(const u16* __restrict__ XC, const u16* __restrict__ XL,
                                               const u16* __restrict__ XH, const float* __restrict__ mask,
                                               const float* __restrict__ lam1, const float* __restrict__ lam2,
                                               const float* __restrict__ lin_w, const float* __restrict__ lin_b,
                                               float* __restrict__ out, int n) {
    int node = blockIdx.x * 4 + (threadIdx.x >> 6);
    if (node >= n) return;
    int lane = threadIdx.x & 63;

    float a0 = lam1[0], a1 = lam1[1];
    float e0 = __expf(a0), e1 = __expf(a1);
    float lamxl = e0 / (e0 + e1), laml = e1 / (e0 + e1);
    float b0 = lam2[0], b1 = lam2[1];
    float f0 = __expf(b0), f1 = __expf(b1);
    float lamxh = f0 / (f0 + f1), lamh = f1 / (f0 + f1);

    bool mi = mask[node] != 0.f;
    float lamx = mi ? lamxl : lamxh;

    const u32* XCr = (const u32*)XC;
    const u32* XLr = (const u32*)XL;
    const u32* XHr = (const u32*)XH;
    float2 xc = unpack2(XCr[(size_t)node * 64 + lane]);
    float2 xl = unpack2(XLr[(size_t)node * 64 + lane]);
    float2 xh = unpack2(XHr[(size_t)node * 64 + lane]);

    float g0 = lamx * xc.x + laml * xl.x + lamh * xh.x; g0 = g0 > 0.f ? g0 : 0.f;
    float g1 = lamx * xc.y + laml * xl.y + lamh * xh.y; g1 = g1 > 0.f ? g1 : 0.f;

    float part[10];
    const float* w0 = lin_w + (size_t)(lane * 2) * 10;
#pragma unroll
    for (int c = 0; c < 10; c++) part[c] = g0 * w0[c] + g1 * w0[10 + c];

#pragma unroll
    for (int off = 32; off > 0; off >>= 1) {
#pragma unroll
        for (int c = 0; c < 10; c++) part[c] += __shfl_down(part[c], off);
    }
    if (lane == 0) {
#pragma unroll
        for (int c = 0; c < 10; c++)
            out[(size_t)node * 10 + c] = part[c] + lin_b[c];
    }
}

// ---------------- launch ----------------

extern "C" void kernel_launch(void* const* d_in, const int* in_sizes, int n_in,
                              void* d_out, int out_size, void* d_ws, size_t ws_size,
                              hipStream_t stream) {
    const float* x = (const float*)d_in[0];
    const int* ei = (const int*)d_in[1];
    const float* mask = (const float*)d_in[2];
    const float* W1L = (const float*)d_in[3];
    const float* W1H = (const float*)d_in[4];
    const float* W2L = (const float*)d_in[5];
    const float* W2H = (const float*)d_in[6];
    const float* WX = (const float*)d_in[7];
    const float* lam1 = (const float*)d_in[8];
    const float* lam2 = (const float*)d_in[9];
    const float* lin_w = (const float*)d_in[10];
    const float* lin_b = (const float*)d_in[11];
    float* out = (float*)d_out;

    int E = in_sizes[1] / 2;
    int n = in_sizes[2];

    char* w = (char*)d_ws;
    size_t off = 0;
    auto alloc = [&](size_t bytes) -> void* {
        off = (off + 255) & ~(size_t)255;
        void* p = w + off;
        off += bytes;
        return p;
    };
    int* cnt = (int*)alloc((size_t)n * 4);
    int* cntm = (int*)alloc((size_t)n * 4);
    int* rowptr = (int*)alloc((size_t)(n + 1) * 4);
    int* cursor = (int*)alloc((size_t)n * 4);
    int* blocksum = (int*)alloc(128 * 4);
    int* blockoff = (int*)alloc(128 * 4);
    int* sorted = (int*)alloc((size_t)E * 4);
    float* dinvL = (float*)alloc((size_t)n * 4);
    float* dinvH = (float*)alloc((size_t)n * 4);
    float* dinvLL = (float*)alloc((size_t)n * 4);
    float* dinvHH = (float*)alloc((size_t)n * 4);
    float* diagL = (float*)alloc((size_t)n * 4);
    float* diagH = (float*)alloc((size_t)n * 4);
    float* diagLL = (float*)alloc((size_t)n * 4);
    float* diagHH = (float*)alloc((size_t)n * 4);
    u16* Bt = (u16*)alloc(5 * 16384 * 2);
    size_t actb = (size_t)n * 128 * 2;
    u16* Xb = (u16*)alloc(actb);
    u16* B0 = (u16*)alloc(actb);
    u16* B1 = (u16*)alloc(actb);
    u16* B2 = (u16*)alloc(actb);
    u16* B3 = (u16*)alloc(actb);

    hipMemsetAsync(cnt, 0, (size_t)n * 4, stream);
    hipMemsetAsync(cntm, 0, (size_t)n * 4, stream);

    int eblk = (E + 255) / 256;
    int nblk256 = (n + 255) / 256;
    int nblkScan = (n + SCAN_B - 1) / SCAN_B;

    cvt_bf16<<<(n * 128 / 4 + 255) / 256, 256, 0, stream>>>(x, Xb, n * 128 / 4);
    edge_stats<<<eblk, 256, 0, stream>>>(ei, mask, cnt, cntm, E);
    scanA<<<nblkScan, 1024, 0, stream>>>(cnt, rowptr, blocksum, n);
    scanB<<<1, 128, 0, stream>>>(blocksum, blockoff, nblkScan, rowptr, n);
    scanC<<<nblk256, 256, 0, stream>>>(rowptr, cursor, blockoff, n);
    norm_kernel<<<nblk256, 256, 0, stream>>>(cnt, cntm, mask, dinvL, dinvH, dinvLL, dinvHH,
                                             diagL, diagH, diagLL, diagHH, n);
    scatter_edges<<<eblk, 256, 0, stream>>>(ei, mask, cursor, sorted, E);

    int rowsblk = (n + 3) / 4;
    int gemmblk = (n + 63) / 64;

    // layer 1: dual spmm from x, then two GEMMs with relu
    spmm1<<<rowsblk, 256, 0, stream>>>(Xb, rowptr, sorted, mask, dinvL, dinvH, diagL, diagH, B0, B1, n);
    transposeW<<<320, 256, 0, stream>>>(W1L, W1H, W2L, W2H, WX, Bt);
    gemm128<<<gemmblk, 256, 0, stream>>>(B0, Bt + 0 * 16384, B2, n, 1);   // XL1
    gemm128<<<gemmblk, 256, 0, stream>>>(B1, Bt + 1 * 16384, B3, n, 1);   // XH1

    // layer 2: dual spmm from XL1/XH1, then two GEMMs
    spmm2<<<rowsblk, 256, 0, stream>>>(B2, B3, rowptr, sorted, dinvLL, dinvHH, diagLL, diagHH, B0, B1, n);
    gemm128<<<gemmblk, 256, 0, stream>>>(B0, Bt + 2 * 16384, B2, n, 0);   // XL
    gemm128<<<gemmblk, 256, 0, stream>>>(B1, Bt + 3 * 16384, B3, n, 0);   // XH

    // xc = x @ WX
    gemm128<<<gemmblk, 256, 0, stream>>>(Xb, Bt + 4 * 16384, B0, n, 0);   // XC

    // fused gate + final linear
    final_k<<<rowsblk, 256, 0, stream>>>(B0, B2, B3, mask, lam1, lam2, lin_w, lin_b, out, n);
}

// Round 3
// 699.552 us; speedup vs baseline: 1.3666x; 1.3666x over previous
//
#include <hip/hip_runtime.h>
#include <stdint.h>

typedef unsigned int u32;
typedef unsigned short u16;

#define DI __device__ __forceinline__

DI float bf2f(u16 u) { union { u32 i; float f; } v; v.i = ((u32)u) << 16; return v.f; }
DI u16 f2bf(float f) {
    union { u32 i; float f; } v; v.f = f;
    u32 u = v.i;
    u32 r = (u + 0x7fffu + ((u >> 16) & 1u)) >> 16;
    return (u16)r;
}
DI float2 unpack2(u32 x) { return make_float2(bf2f((u16)(x & 0xffffu)), bf2f((u16)(x >> 16))); }
DI u32 pack2(float a, float b) { return (u32)f2bf(a) | ((u32)f2bf(b) << 16); }

DI void fma8(float* acc, float w, uint4 xv) {
    float2 f0 = unpack2(xv.x), f1 = unpack2(xv.y), f2 = unpack2(xv.z), f3 = unpack2(xv.w);
    acc[0] += w * f0.x; acc[1] += w * f0.y; acc[2] += w * f1.x; acc[3] += w * f1.y;
    acc[4] += w * f2.x; acc[5] += w * f2.y; acc[6] += w * f3.x; acc[7] += w * f3.y;
}

// ---------------- convert x (f32) -> bf16 ----------------

__global__ void cvt_bf16(const float* __restrict__ X, u16* __restrict__ Xb, int total4) {
    int i = blockIdx.x * blockDim.x + threadIdx.x;
    if (i >= total4) return;
    float4 v = ((const float4*)X)[i];
    ushort4 o;
    o.x = f2bf(v.x); o.y = f2bf(v.y); o.z = f2bf(v.z); o.w = f2bf(v.w);
    ((ushort4*)Xb)[i] = o;
}

// ---------------- CSR build ----------------

__global__ void edge_stats(const int* __restrict__ ei, const float* __restrict__ mask,
                           int* __restrict__ cnt, int* __restrict__ cntm, int E) {
    int e = blockIdx.x * blockDim.x + threadIdx.x;
    if (e >= E) return;
    int c = ei[e];          // src (col)
    int r = ei[E + e];      // dst (row)
    if (r != c) {
        atomicAdd(&cnt[r], 1);
        if (mask[c] != 0.f) atomicAdd(&cntm[r], 1);
    }
}

#define SCAN_B 1024
__global__ __launch_bounds__(1024) void scanA(const int* __restrict__ cnt, int* __restrict__ rowptr,
                                              int* __restrict__ blocksum, int n) {
    __shared__ int s[SCAN_B];
    int t = threadIdx.x;
    int i = blockIdx.x * SCAN_B + t;
    int v = (i < n) ? cnt[i] : 0;
    s[t] = v; __syncthreads();
    for (int off = 1; off < SCAN_B; off <<= 1) {
        int tmp = (t >= off) ? s[t - off] : 0;
        __syncthreads();
        s[t] += tmp;
        __syncthreads();
    }
    if (i < n) rowptr[i] = s[t] - v;   // local exclusive
    if (t == SCAN_B - 1) blocksum[blockIdx.x] = s[t];
}

__global__ void scanB(const int* __restrict__ blocksum, int* __restrict__ blockoff,
                      int nblk, int* __restrict__ rowptr, int n) {
    __shared__ int s[128];
    int t = threadIdx.x;
    int v = (t < nblk) ? blocksum[t] : 0;
    s[t] = v; __syncthreads();
    for (int off = 1; off < 128; off <<= 1) {
        int tmp = (t >= off) ? s[t - off] : 0;
        __syncthreads();
        s[t] += tmp;
        __syncthreads();
    }
    if (t < nblk) blockoff[t] = s[t] - v;
    if (t == 127) rowptr[n] = s[127];
}

__global__ void scanC(int* __restrict__ rowptr, int* __restrict__ cursor,
                      const int* __restrict__ blockoff, int n) {
    int i = blockIdx.x * blockDim.x + threadIdx.x;
    if (i < n) {
        int v = rowptr[i] + blockoff[i >> 10];
        rowptr[i] = v;
        cursor[i] = v;
    }
}

__global__ void scatter_edges(const int* __restrict__ ei, const float* __restrict__ mask,
                              int* __restrict__ cursor, int* __restrict__ sorted, int E) {
    int e = blockIdx.x * blockDim.x + threadIdx.x;
    if (e >= E) return;
    int c = ei[e];
    int r = ei[E + e];
    if (r != c) {
        int pos = atomicAdd(&cursor[r], 1);
        sorted[pos] = c | ((mask[c] != 0.f) ? (int)0x80000000 : 0);
    }
}

// ---------------- per-node normalization ----------------

__global__ void norm_kernel(const int* __restrict__ cnt, const int* __restrict__ cntm,
                            const float* __restrict__ mask,
                            float* __restrict__ dinvL, float* __restrict__ dinvH,
                            float2* __restrict__ dinv2,   // (dinvLL, dinvHH)
                            float* __restrict__ diagL, float* __restrict__ diagH,
                            float* __restrict__ diagLL, float* __restrict__ diagHH, int n) {
    int i = blockIdx.x * blockDim.x + threadIdx.x;
    if (i >= n) return;
    float c = (float)cnt[i];
    float cm = (float)cntm[i];
    bool mi = mask[i] != 0.f;
    float degL = (mi ? c : 0.f) + 1.f;
    float degH = (mi ? 0.f : c) + 1.f;
    float degLL = cm + 1.f;
    float degHH = (c - cm) + 1.f;
    dinvL[i] = rsqrtf(degL);   diagL[i] = 1.f / degL;
    dinvH[i] = rsqrtf(degH);   diagH[i] = 1.f / degH;
    dinv2[i] = make_float2(rsqrtf(degLL), rsqrtf(degHH));
    diagLL[i] = 1.f / degLL;
    diagHH[i] = 1.f / degHH;
}

// ---------------- SpMM layer 1: quad-per-edge, dwordx4 gathers ----------------
// Wave = 1 row; 4 quads each process a different edge per iter; 16 lanes x 16B = full row.

__global__ __launch_bounds__(256) void spmm1(const u16* __restrict__ X,
                                             const int* __restrict__ rowptr, const int* __restrict__ sorted,
                                             const float* __restrict__ mask,
                                             const float* __restrict__ dinvL, const float* __restrict__ dinvH,
                                             const float* __restrict__ diagL, const float* __restrict__ diagH,
                                             u16* __restrict__ Yl, u16* __restrict__ Yh, int n) {
    int r = blockIdx.x * 4 + (threadIdx.x >> 6);
    if (r >= n) return;
    int lane = threadIdx.x & 63;
    int q = lane >> 4, l16 = lane & 15;
    bool mi = mask[r] != 0.f;
    const float* dinvA = mi ? dinvL : dinvH;
    float da = dinvA[r];
    float diag = mi ? diagL[r] : diagH[r];

    const uint4* Xv = (const uint4*)X;           // row stride = 16 uint4
    uint4 xown = Xv[(size_t)r * 16 + l16];

    float acc[8] = {0.f, 0.f, 0.f, 0.f, 0.f, 0.f, 0.f, 0.f};
    int e0 = rowptr[r], e1 = rowptr[r + 1];
#pragma unroll 2
    for (int base = e0; base < e1; base += 4) {
        int slot = base + q;
        int p = sorted[slot < e1 ? slot : e1 - 1];
        int c = p & 0x7FFFFFFF;
        float w = (slot < e1) ? da * dinvA[c] : 0.f;
        uint4 xv = Xv[(size_t)c * 16 + l16];
        fma8(acc, w, xv);
    }
#pragma unroll
    for (int k = 0; k < 8; k++) {
        acc[k] += __shfl_xor(acc[k], 16);
        acc[k] += __shfl_xor(acc[k], 32);
    }
    // add diag * own row
    float2 o0 = unpack2(xown.x), o1 = unpack2(xown.y), o2 = unpack2(xown.z), o3 = unpack2(xown.w);
    uint4 res;
    res.x = pack2(acc[0] + diag * o0.x, acc[1] + diag * o0.y);
    res.y = pack2(acc[2] + diag * o1.x, acc[3] + diag * o1.y);
    res.z = pack2(acc[4] + diag * o2.x, acc[5] + diag * o2.y);
    res.w = pack2(acc[6] + diag * o3.x, acc[7] + diag * o3.y);
    uint4* Ya = (uint4*)(mi ? Yl : Yh);
    uint4* Yc = (uint4*)(mi ? Yh : Yl);
    if (q == 0) Ya[(size_t)r * 16 + l16] = res;
    if (q == 1) Yc[(size_t)r * 16 + l16] = xown;   // deg=1, diag=1 -> exact copy
}

// ---------------- SpMM layer 2: quad-per-edge, per-lane src-matrix select ----------------

__global__ __launch_bounds__(256) void spmm2(const u16* __restrict__ XL, const u16* __restrict__ XH,
                                             const int* __restrict__ rowptr, const int* __restrict__ sorted,
                                             const float2* __restrict__ dinv2,
                                             const float* __restrict__ diagLL, const float* __restrict__ diagHH,
                                             u16* __restrict__ Zl, u16* __restrict__ Zh, int n) {
    int r = blockIdx.x * 4 + (threadIdx.x >> 6);
    if (r >= n) return;
    int lane = threadIdx.x & 63;
    int q = lane >> 4, l16 = lane & 15;

    float2 dr = dinv2[r];
    float dllr = dr.x, dhhr = dr.y;
    float cl = diagLL[r], ch = diagHH[r];

    const uint4* XLv = (const uint4*)XL;
    const uint4* XHv = (const uint4*)XH;
    uint4 xlown = XLv[(size_t)r * 16 + l16];
    uint4 xhown = XHv[(size_t)r * 16 + l16];

    float accL[8] = {0.f, 0.f, 0.f, 0.f, 0.f, 0.f, 0.f, 0.f};
    float accH[8] = {0.f, 0.f, 0.f, 0.f, 0.f, 0.f, 0.f, 0.f};
    int e0 = rowptr[r], e1 = rowptr[r + 1];
#pragma unroll 2
    for (int base = e0; base < e1; base += 4) {
        int slot = base + q;
        int p = sorted[slot < e1 ? slot : e1 - 1];
        int c = p & 0x7FFFFFFF;
        bool isL = p < 0;
        float2 dc = dinv2[c];
        float w = isL ? dllr * dc.x : dhhr * dc.y;
        if (slot >= e1) w = 0.f;
        float wl = isL ? w : 0.f;
        float wh = isL ? 0.f : w;
        const uint4* src = isL ? XLv : XHv;
        uint4 xv = src[(size_t)c * 16 + l16];
        fma8(accL, wl, xv);
        fma8(accH, wh, xv);
    }
#pragma unroll
    for (int k = 0; k < 8; k++) {
        accL[k] += __shfl_xor(accL[k], 16);
        accL[k] += __shfl_xor(accL[k], 32);
        accH[k] += __shfl_xor(accH[k], 16);
        accH[k] += __shfl_xor(accH[k], 32);
    }
    float2 l0 = unpack2(xlown.x), l1 = unpack2(xlown.y), l2 = unpack2(xlown.z), l3 = unpack2(xlown.w);
    float2 h0 = unpack2(xhown.x), h1 = unpack2(xhown.y), h2 = unpack2(xhown.z), h3 = unpack2(xhown.w);
    uint4 rl, rh;
    rl.x = pack2(accL[0] + cl * l0.x, accL[1] + cl * l0.y);
    rl.y = pack2(accL[2] + cl * l1.x, accL[3] + cl * l1.y);
    rl.z = pack2(accL[4] + cl * l2.x, accL[5] + cl * l2.y);
    rl.w = pack2(accL[6] + cl * l3.x, accL[7] + cl * l3.y);
    rh.x = pack2(accH[0] + ch * h0.x, accH[1] + ch * h0.y);
    rh.y = pack2(accH[2] + ch * h1.x, accH[3] + ch * h1.y);
    rh.z = pack2(accH[4] + ch * h2.x, accH[5] + ch * h2.y);
    rh.w = pack2(accH[6] + ch * h3.x, accH[7] + ch * h3.y);
    if (q == 0) ((uint4*)Zl)[(size_t)r * 16 + l16] = rl;
    if (q == 1) ((uint4*)Zh)[(size_t)r * 16 + l16] = rh;
}

// ---------------- weight transpose f32 -> bf16 (Bt[n][k] contiguous in k) ----------------

__global__ void transposeW(const float* __restrict__ W1L, const float* __restrict__ W1H,
                           const float* __restrict__ W2L, const float* __restrict__ W2H,
                           const float* __restrict__ WX, u16* __restrict__ Bt) {
    int w = blockIdx.x >> 6;                         // which weight
    int idx = (blockIdx.x & 63) * 256 + threadIdx.x; // 0..16383
    const float* src = (w == 0) ? W1L : (w == 1) ? W1H : (w == 2) ? W2L : (w == 3) ? W2H : WX;
    int k = idx >> 7, nn = idx & 127;
    Bt[(size_t)w * 16384 + (size_t)nn * 128 + k] = f2bf(src[idx]);
}

// ---------------- MFMA GEMM: C[M,128] = op(A[M,128] @ B[128,128]) ----------------

typedef __attribute__((ext_vector_type(8))) short bf16x8;
typedef __attribute__((ext_vector_type(4))) float f32x4;

DI void gemm_core(const u16* __restrict__ A, const u16* __restrict__ Bt, u16* __restrict__ C,
                  int M, int do_relu, int bx, int tid) {
    int wave = tid >> 6;
    int lane = tid & 63;
    int quad = lane >> 4;
    int l16 = lane & 15;
    int m0 = bx * 64 + wave * 16 + l16;

    bf16x8 afrag[4];
    bf16x8 zero = {0, 0, 0, 0, 0, 0, 0, 0};
    if (m0 < M) {
        const u16* arow = A + (size_t)m0 * 128 + quad * 8;
#pragma unroll
        for (int kb = 0; kb < 4; kb++)
            afrag[kb] = *(const bf16x8*)(arow + kb * 32);
    } else {
#pragma unroll
        for (int kb = 0; kb < 4; kb++) afrag[kb] = zero;
    }

    f32x4 acc[8];
#pragma unroll
    for (int nt = 0; nt < 8; nt++) acc[nt] = f32x4{0.f, 0.f, 0.f, 0.f};

#pragma unroll
    for (int nt = 0; nt < 8; nt++) {
        const u16* brow = Bt + (size_t)(nt * 16 + l16) * 128 + quad * 8;
#pragma unroll
        for (int kb = 0; kb < 4; kb++) {
            bf16x8 b = *(const bf16x8*)(brow + kb * 32);
            acc[nt] = __builtin_amdgcn_mfma_f32_16x16x32_bf16(afrag[kb], b, acc[nt], 0, 0, 0);
        }
    }

    int rbase = bx * 64 + wave * 16 + quad * 4;
#pragma unroll
    for (int nt = 0; nt < 8; nt++) {
#pragma unroll
        for (int rr = 0; rr < 4; rr++) {
            int row = rbase + rr;
            if (row < M) {
                float v = acc[nt][rr];
                if (do_relu) v = v > 0.f ? v : 0.f;
                C[(size_t)row * 128 + nt * 16 + l16] = f2bf(v);
            }
        }
    }
}

__global__ __launch_bounds__(256) void gemm128(const u16* __restrict__ A, const u16* __restrict__ Bt,
                                               u16* __restrict__ C, int M, int do_relu) {
    gemm_core(A, Bt, C, M, do_relu, blockIdx.x, threadIdx.x);
}

__global__ __launch_bounds__(256) void gemm128x2(const u16* A0, const u16* Bt0, u16* C0,
                                                 const u16* A1, const u16* Bt1, u16* C1,
                                                 int M, int do_relu) {
    if (blockIdx.y == 0) gemm_core(A0, Bt0, C0, M, do_relu, blockIdx.x, threadIdx.x);
    else                 gemm_core(A1, Bt1, C1, M, do_relu, blockIdx.x, threadIdx.x);
}

// ---------------- fused gate + [N,128]x[128,10] epilogue (f32 out) ----------------

__global__ __launch_bounds__(256) void final_k(const u16* __restrict__ XC, const u16* __restrict__ XL,
                                               const u16* __restrict__ XH, const float* __restrict__ mask,
                                               const float* __restrict__ lam1, const float* __restrict__ lam2,
                                               const float* __restrict__ lin_w, const float* __restrict__ lin_b,
                                               float* __restrict__ out, int n) {
    int node = blockIdx.x * 4 + (threadIdx.x >> 6);
    if (node >= n) return;
    int lane = threadIdx.x & 63;

    float a0 = lam1[0], a1 = lam1[1];
    float e0 = __expf(a0), e1 = __expf(a1);
    float lamxl = e0 / (e0 + e1), laml = e1 / (e0 + e1);
    float b0 = lam2[0], b1 = lam2[1];
    float f0 = __expf(b0), f1 = __expf(b1);
    float lamxh = f0 / (f0 + f1), lamh = f1 / (f0 + f1);

    bool mi = mask[node] != 0.f;
    float lamx = mi ? lamxl : lamxh;

    const u32* XCr = (const u32*)XC;
    const u32* XLr = (const u32*)XL;
    const u32* XHr = (const u32*)XH;
    float2 xc = unpack2(XCr[(size_t)node * 64 + lane]);
    float2 xl = unpack2(XLr[(size_t)node * 64 + lane]);
    float2 xh = unpack2(XHr[(size_t)node * 64 + lane]);

    float g0 = lamx * xc.x + laml * xl.x + lamh * xh.x; g0 = g0 > 0.f ? g0 : 0.f;
    float g1 = lamx * xc.y + laml * xl.y + lamh * xh.y; g1 = g1 > 0.f ? g1 : 0.f;

    float part[10];
    const float* w0 = lin_w + (size_t)(lane * 2) * 10;
#pragma unroll
    for (int c = 0; c < 10; c++) part[c] = g0 * w0[c] + g1 * w0[10 + c];

#pragma unroll
    for (int off = 32; off > 0; off >>= 1) {
#pragma unroll
        for (int c = 0; c < 10; c++) part[c] += __shfl_down(part[c], off);
    }
    if (lane == 0) {
#pragma unroll
        for (int c = 0; c < 10; c++)
            out[(size_t)node * 10 + c] = part[c] + lin_b[c];
    }
}

// ---------------- launch ----------------

extern "C" void kernel_launch(void* const* d_in, const int* in_sizes, int n_in,
                              void* d_out, int out_size, void* d_ws, size_t ws_size,
                              hipStream_t stream) {
    const float* x = (const float*)d_in[0];
    const int* ei = (const int*)d_in[1];
    const float* mask = (const float*)d_in[2];
    const float* W1L = (const float*)d_in[3];
    const float* W1H = (const float*)d_in[4];
    const float* W2L = (const float*)d_in[5];
    const float* W2H = (const float*)d_in[6];
    const float* WX = (const float*)d_in[7];
    const float* lam1 = (const float*)d_in[8];
    const float* lam2 = (const float*)d_in[9];
    const float* lin_w = (const float*)d_in[10];
    const float* lin_b = (const float*)d_in[11];
    float* out = (float*)d_out;

    int E = in_sizes[1] / 2;
    int n = in_sizes[2];

    char* w = (char*)d_ws;
    size_t off = 0;
    auto alloc = [&](size_t bytes) -> void* {
        off = (off + 255) & ~(size_t)255;
        void* p = w + off;
        off += bytes;
        return p;
    };
    int* cnt = (int*)alloc((size_t)n * 4);
    int* cntm = (int*)alloc((size_t)n * 4);
    int* rowptr = (int*)alloc((size_t)(n + 1) * 4);
    int* cursor = (int*)alloc((size_t)n * 4);
    int* blocksum = (int*)alloc(128 * 4);
    int* blockoff = (int*)alloc(128 * 4);
    int* sorted = (int*)alloc((size_t)E * 4);
    float* dinvL = (float*)alloc((size_t)n * 4);
    float* dinvH = (float*)alloc((size_t)n * 4);
    float2* dinv2 = (float2*)alloc((size_t)n * 8);
    float* diagL = (float*)alloc((size_t)n * 4);
    float* diagH = (float*)alloc((size_t)n * 4);
    float* diagLL = (float*)alloc((size_t)n * 4);
    float* diagHH = (float*)alloc((size_t)n * 4);
    u16* Bt = (u16*)alloc(5 * 16384 * 2);
    size_t actb = (size_t)n * 128 * 2;
    u16* Xb = (u16*)alloc(actb);
    u16* B0 = (u16*)alloc(actb);
    u16* B1 = (u16*)alloc(actb);
    u16* B2 = (u16*)alloc(actb);
    u16* B3 = (u16*)alloc(actb);

    hipMemsetAsync(cnt, 0, (size_t)n * 4, stream);
    hipMemsetAsync(cntm, 0, (size_t)n * 4, stream);

    int eblk = (E + 255) / 256;
    int nblk256 = (n + 255) / 256;
    int nblkScan = (n + SCAN_B - 1) / SCAN_B;

    cvt_bf16<<<(n * 128 / 4 + 255) / 256, 256, 0, stream>>>(x, Xb, n * 128 / 4);
    edge_stats<<<eblk, 256, 0, stream>>>(ei, mask, cnt, cntm, E);
    scanA<<<nblkScan, 1024, 0, stream>>>(cnt, rowptr, blocksum, n);
    scanB<<<1, 128, 0, stream>>>(blocksum, blockoff, nblkScan, rowptr, n);
    scanC<<<nblk256, 256, 0, stream>>>(rowptr, cursor, blockoff, n);
    norm_kernel<<<nblk256, 256, 0, stream>>>(cnt, cntm, mask, dinvL, dinvH, dinv2,
                                             diagL, diagH, diagLL, diagHH, n);
    scatter_edges<<<eblk, 256, 0, stream>>>(ei, mask, cursor, sorted, E);

    int rowsblk = (n + 3) / 4;
    int gemmblk = (n + 63) / 64;

    // layer 1: dual spmm from x, then two GEMMs with relu (batched)
    spmm1<<<rowsblk, 256, 0, stream>>>(Xb, rowptr, sorted, mask, dinvL, dinvH, diagL, diagH, B0, B1, n);
    transposeW<<<320, 256, 0, stream>>>(W1L, W1H, W2L, W2H, WX, Bt);
    gemm128x2<<<dim3(gemmblk, 2), 256, 0, stream>>>(B0, Bt + 0 * 16384, B2,
                                                    B1, Bt + 1 * 16384, B3, n, 1);

    // layer 2: dual spmm from XL1/XH1, then two GEMMs (batched)
    spmm2<<<rowsblk, 256, 0, stream>>>(B2, B3, rowptr, sorted, dinv2, diagLL, diagHH, B0, B1, n);
    gemm128x2<<<dim3(gemmblk, 2), 256, 0, stream>>>(B0, Bt + 2 * 16384, B2,
                                                    B1, Bt + 3 * 16384, B3, n, 0);

    // xc = x @ WX (B0 free after layer-2 gemms read it)
    gemm128<<<gemmblk, 256, 0, stream>>>(Xb, Bt + 4 * 16384, B0, n, 0);   // XC

    // fused gate + final linear
    final_k<<<rowsblk, 256, 0, stream>>>(B0, B2, B3, mask, lam1, lam2, lin_w, lin_b, out, n);
}

// Round 4
// 609.517 us; speedup vs baseline: 1.5685x; 1.1477x over previous
//
#include <hip/hip_runtime.h>
#include <stdint.h>

typedef unsigned int u32;
typedef unsigned short u16;

#define DI __device__ __forceinline__

DI float bf2f(u16 u) { union { u32 i; float f; } v; v.i = ((u32)u) << 16; return v.f; }
DI u16 f2bf(float f) {
    union { u32 i; float f; } v; v.f = f;
    u32 u = v.i;
    u32 r = (u + 0x7fffu + ((u >> 16) & 1u)) >> 16;
    return (u16)r;
}
DI float2 unpack2(u32 x) { return make_float2(bf2f((u16)(x & 0xffffu)), bf2f((u16)(x >> 16))); }
DI u32 pack2(float a, float b) { return (u32)f2bf(a) | ((u32)f2bf(b) << 16); }

DI void fma8(float* acc, float w, uint4 xv) {
    float2 f0 = unpack2(xv.x), f1 = unpack2(xv.y), f2 = unpack2(xv.z), f3 = unpack2(xv.w);
    acc[0] += w * f0.x; acc[1] += w * f0.y; acc[2] += w * f1.x; acc[3] += w * f1.y;
    acc[4] += w * f2.x; acc[5] += w * f2.y; acc[6] += w * f3.x; acc[7] += w * f3.y;
}

// ---------------- convert x (f32) -> bf16 ----------------

__global__ void cvt_bf16(const float* __restrict__ X, u16* __restrict__ Xb, int total4) {
    int i = blockIdx.x * blockDim.x + threadIdx.x;
    if (i >= total4) return;
    float4 v = ((const float4*)X)[i];
    ushort4 o;
    o.x = f2bf(v.x); o.y = f2bf(v.y); o.z = f2bf(v.z); o.w = f2bf(v.w);
    ((ushort4*)Xb)[i] = o;
}

// ---------------- CSR build ----------------

__global__ void edge_stats(const int* __restrict__ ei, const float* __restrict__ mask,
                           int* __restrict__ cnt, int* __restrict__ cntm, int E) {
    int e = blockIdx.x * blockDim.x + threadIdx.x;
    if (e >= E) return;
    int c = ei[e];          // src (col)
    int r = ei[E + e];      // dst (row)
    if (r != c) {
        atomicAdd(&cnt[r], 1);
        if (mask[c] != 0.f) atomicAdd(&cntm[r], 1);
    }
}

#define SCAN_B 1024
__global__ __launch_bounds__(1024) void scanA(const int* __restrict__ cnt, int* __restrict__ rowptr,
                                              int* __restrict__ blocksum, int n) {
    __shared__ int s[SCAN_B];
    int t = threadIdx.x;
    int i = blockIdx.x * SCAN_B + t;
    int v = (i < n) ? cnt[i] : 0;
    s[t] = v; __syncthreads();
    for (int off = 1; off < SCAN_B; off <<= 1) {
        int tmp = (t >= off) ? s[t - off] : 0;
        __syncthreads();
        s[t] += tmp;
        __syncthreads();
    }
    if (i < n) rowptr[i] = s[t] - v;   // local exclusive
    if (t == SCAN_B - 1) blocksum[blockIdx.x] = s[t];
}

__global__ void scanB(const int* __restrict__ blocksum, int* __restrict__ blockoff,
                      int nblk, int* __restrict__ rowptr, int n) {
    __shared__ int s[128];
    int t = threadIdx.x;
    int v = (t < nblk) ? blocksum[t] : 0;
    s[t] = v; __syncthreads();
    for (int off = 1; off < 128; off <<= 1) {
        int tmp = (t >= off) ? s[t - off] : 0;
        __syncthreads();
        s[t] += tmp;
        __syncthreads();
    }
    if (t < nblk) blockoff[t] = s[t] - v;
    if (t == 127) rowptr[n] = s[127];
}

// scanC fused with norm: finalize rowptr, init cursors, mid-split, all degree factors
__global__ void scanC(int* __restrict__ rowptr, const int* __restrict__ blockoff,
                      const int* __restrict__ cnt, const int* __restrict__ cntm,
                      const float* __restrict__ mask,
                      int* __restrict__ cursL, int* __restrict__ cursH, int* __restrict__ mid,
                      float* __restrict__ dinvL, float* __restrict__ dinvH,
                      float* __restrict__ dinvLL, float* __restrict__ dinvHH,
                      float2* __restrict__ diag1, float2* __restrict__ diag2, int n) {
    int i = blockIdx.x * blockDim.x + threadIdx.x;
    if (i >= n) return;
    int v = rowptr[i] + blockoff[i >> 10];
    rowptr[i] = v;
    cursL[i] = v;
    cursH[i] = 0;
    float c = (float)cnt[i];
    float cm = (float)cntm[i];
    mid[i] = v + cntm[i];
    bool mi = mask[i] != 0.f;
    float degL = (mi ? c : 0.f) + 1.f;
    float degH = (mi ? 0.f : c) + 1.f;
    float degLL = cm + 1.f;
    float degHH = (c - cm) + 1.f;
    dinvL[i] = rsqrtf(degL);
    dinvH[i] = rsqrtf(degH);
    dinvLL[i] = rsqrtf(degLL);
    dinvHH[i] = rsqrtf(degHH);
    diag1[i] = make_float2(1.f / degL, 1.f / degH);
    diag2[i] = make_float2(1.f / degLL, 1.f / degHH);
}

// scatter with per-row partition: masked-src edges from front, unmasked from mid
__global__ void scatter_edges(const int* __restrict__ ei, const float* __restrict__ mask,
                              int* __restrict__ cursL, int* __restrict__ cursH,
                              const int* __restrict__ mid,
                              int* __restrict__ sorted, int E) {
    int e = blockIdx.x * blockDim.x + threadIdx.x;
    if (e >= E) return;
    int c = ei[e];
    int r = ei[E + e];
    if (r != c) {
        int pos;
        if (mask[c] != 0.f) pos = atomicAdd(&cursL[r], 1);
        else                pos = mid[r] + atomicAdd(&cursH[r], 1);
        sorted[pos] = c;
    }
}

// ---------------- SpMM layer 1: quad-per-edge, branchless 8-edge bodies ----------------

__global__ __launch_bounds__(256) void spmm1(const u16* __restrict__ X,
                                             const int* __restrict__ rowptr, const int* __restrict__ sorted,
                                             const float* __restrict__ mask,
                                             const float* __restrict__ dinvL, const float* __restrict__ dinvH,
                                             const float2* __restrict__ diag1,
                                             u16* __restrict__ Yl, u16* __restrict__ Yh, int n) {
    int r = blockIdx.x * 4 + (threadIdx.x >> 6);
    if (r >= n) return;
    int lane = threadIdx.x & 63;
    int q = lane >> 4, l16 = lane & 15;
    bool mi = mask[r] != 0.f;
    const float* dinvA = mi ? dinvL : dinvH;
    float da = dinvA[r];
    float2 dg = diag1[r];
    float diag = mi ? dg.x : dg.y;

    const uint4* Xv = (const uint4*)X;
    uint4 xown = Xv[(size_t)r * 16 + l16];

    float acc[8] = {0.f, 0.f, 0.f, 0.f, 0.f, 0.f, 0.f, 0.f};
    int e0 = rowptr[r], e1 = rowptr[r + 1];
    int last = e1 - 1;
    for (int base = e0; base < e1; base += 8) {
        int s0 = base + q, s1 = base + 4 + q;
        int i0 = min(s0, last), i1 = min(s1, last);
        int c0 = sorted[i0], c1 = sorted[i1];
        float w0 = (s0 < e1) ? da * dinvA[c0] : 0.f;
        float w1 = (s1 < e1) ? da * dinvA[c1] : 0.f;
        uint4 x0 = Xv[(size_t)c0 * 16 + l16];
        uint4 x1 = Xv[(size_t)c1 * 16 + l16];
        fma8(acc, w0, x0);
        fma8(acc, w1, x1);
    }
#pragma unroll
    for (int k = 0; k < 8; k++) {
        acc[k] += __shfl_xor(acc[k], 16);
        acc[k] += __shfl_xor(acc[k], 32);
    }
    float2 o0 = unpack2(xown.x), o1 = unpack2(xown.y), o2 = unpack2(xown.z), o3 = unpack2(xown.w);
    uint4 res;
    res.x = pack2(acc[0] + diag * o0.x, acc[1] + diag * o0.y);
    res.y = pack2(acc[2] + diag * o1.x, acc[3] + diag * o1.y);
    res.z = pack2(acc[4] + diag * o2.x, acc[5] + diag * o2.y);
    res.w = pack2(acc[6] + diag * o3.x, acc[7] + diag * o3.y);
    uint4* Ya = (uint4*)(mi ? Yl : Yh);
    uint4* Yc = (uint4*)(mi ? Yh : Yl);
    if (q == 0) Ya[(size_t)r * 16 + l16] = res;
    if (q == 1) Yc[(size_t)r * 16 + l16] = xown;   // deg=1, diag=1 -> exact copy
}

// ---------------- SpMM layer 2: partitioned rows, two uniform phases ----------------

__global__ __launch_bounds__(256) void spmm2(const u16* __restrict__ XL, const u16* __restrict__ XH,
                                             const int* __restrict__ rowptr, const int* __restrict__ mid,
                                             const int* __restrict__ sorted,
                                             const float* __restrict__ dinvLL, const float* __restrict__ dinvHH,
                                             const float2* __restrict__ diag2,
                                             u16* __restrict__ Zl, u16* __restrict__ Zh, int n) {
    int r = blockIdx.x * 4 + (threadIdx.x >> 6);
    if (r >= n) return;
    int lane = threadIdx.x & 63;
    int q = lane >> 4, l16 = lane & 15;

    float dllr = dinvLL[r], dhhr = dinvHH[r];
    float2 dg = diag2[r];

    const uint4* XLv = (const uint4*)XL;
    const uint4* XHv = (const uint4*)XH;
    uint4 xlown = XLv[(size_t)r * 16 + l16];
    uint4 xhown = XHv[(size_t)r * 16 + l16];

    float accL[8] = {0.f, 0.f, 0.f, 0.f, 0.f, 0.f, 0.f, 0.f};
    float accH[8] = {0.f, 0.f, 0.f, 0.f, 0.f, 0.f, 0.f, 0.f};
    int e0 = rowptr[r], m = mid[r], e1 = rowptr[r + 1];

    // L phase: edges [e0, m), sources masked -> XL with dinvLL
    int lastL = m - 1;
    for (int base = e0; base < m; base += 8) {
        int s0 = base + q, s1 = base + 4 + q;
        int i0 = min(s0, lastL), i1 = min(s1, lastL);
        int c0 = sorted[i0], c1 = sorted[i1];
        float w0 = (s0 < m) ? dllr * dinvLL[c0] : 0.f;
        float w1 = (s1 < m) ? dllr * dinvLL[c1] : 0.f;
        uint4 x0 = XLv[(size_t)c0 * 16 + l16];
        uint4 x1 = XLv[(size_t)c1 * 16 + l16];
        fma8(accL, w0, x0);
        fma8(accL, w1, x1);
    }
    // H phase: edges [m, e1), sources unmasked -> XH with dinvHH
    int lastH = e1 - 1;
    for (int base = m; base < e1; base += 8) {
        int s0 = base + q, s1 = base + 4 + q;
        int i0 = min(s0, lastH), i1 = min(s1, lastH);
        int c0 = sorted[i0], c1 = sorted[i1];
        float w0 = (s0 < e1) ? dhhr * dinvHH[c0] : 0.f;
        float w1 = (s1 < e1) ? dhhr * dinvHH[c1] : 0.f;
        uint4 x0 = XHv[(size_t)c0 * 16 + l16];
        uint4 x1 = XHv[(size_t)c1 * 16 + l16];
        fma8(accH, w0, x0);
        fma8(accH, w1, x1);
    }
#pragma unroll
    for (int k = 0; k < 8; k++) {
        accL[k] += __shfl_xor(accL[k], 16);
        accL[k] += __shfl_xor(accL[k], 32);
        accH[k] += __shfl_xor(accH[k], 16);
        accH[k] += __shfl_xor(accH[k], 32);
    }
    float2 l0 = unpack2(xlown.x), l1 = unpack2(xlown.y), l2 = unpack2(xlown.z), l3 = unpack2(xlown.w);
    float2 h0 = unpack2(xhown.x), h1 = unpack2(xhown.y), h2 = unpack2(xhown.z), h3 = unpack2(xhown.w);
    float cl = dg.x, ch = dg.y;
    uint4 rl, rh;
    rl.x = pack2(accL[0] + cl * l0.x, accL[1] + cl * l0.y);
    rl.y = pack2(accL[2] + cl * l1.x, accL[3] + cl * l1.y);
    rl.z = pack2(accL[4] + cl * l2.x, accL[5] + cl * l2.y);
    rl.w = pack2(accL[6] + cl * l3.x, accL[7] + cl * l3.y);
    rh.x = pack2(accH[0] + ch * h0.x, accH[1] + ch * h0.y);
    rh.y = pack2(accH[2] + ch * h1.x, accH[3] + ch * h1.y);
    rh.z = pack2(accH[4] + ch * h2.x, accH[5] + ch * h2.y);
    rh.w = pack2(accH[6] + ch * h3.x, accH[7] + ch * h3.y);
    if (q == 0) ((uint4*)Zl)[(size_t)r * 16 + l16] = rl;
    if (q == 1) ((uint4*)Zh)[(size_t)r * 16 + l16] = rh;
}

// ---------------- weight transpose f32 -> bf16, lam folded into W2L/W2H ----------------

__global__ void transposeW(const float* __restrict__ W1L, const float* __restrict__ W1H,
                           const float* __restrict__ W2L, const float* __restrict__ W2H,
                           const float* __restrict__ WX,
                           const float* __restrict__ lam1, const float* __restrict__ lam2,
                           u16* __restrict__ Bt) {
    int w = blockIdx.x >> 6;                         // which weight
    int idx = (blockIdx.x & 63) * 256 + threadIdx.x; // 0..16383
    float scale = 1.f;
    if (w == 2) { float e0 = __expf(lam1[0]), e1 = __expf(lam1[1]); scale = e1 / (e0 + e1); }
    if (w == 3) { float f0 = __expf(lam2[0]), f1 = __expf(lam2[1]); scale = f1 / (f0 + f1); }
    const float* src = (w == 0) ? W1L : (w == 1) ? W1H : (w == 2) ? W2L : (w == 3) ? W2H : WX;
    int k = idx >> 7, nn = idx & 127;
    Bt[(size_t)w * 16384 + (size_t)nn * 128 + k] = f2bf(scale * src[idx]);
}

// ---------------- MFMA GEMM: C[M,128] = op(A[M,128] @ B[128,128]) ----------------

typedef __attribute__((ext_vector_type(8))) short bf16x8;
typedef __attribute__((ext_vector_type(4))) float f32x4;

DI void load_afrag(bf16x8* afrag, const u16* __restrict__ A, int m0, int M, int quad) {
    bf16x8 zero = {0, 0, 0, 0, 0, 0, 0, 0};
    if (m0 < M) {
        const u16* arow = A + (size_t)m0 * 128 + quad * 8;
#pragma unroll
        for (int kb = 0; kb < 4; kb++)
            afrag[kb] = *(const bf16x8*)(arow + kb * 32);
    } else {
#pragma unroll
        for (int kb = 0; kb < 4; kb++) afrag[kb] = zero;
    }
}

DI void gemm_core(const u16* __restrict__ A, const u16* __restrict__ Bt, u16* __restrict__ C,
                  int M, int do_relu, int bx, int tid) {
    int wave = tid >> 6;
    int lane = tid & 63;
    int quad = lane >> 4;
    int l16 = lane & 15;
    int m0 = bx * 64 + wave * 16 + l16;

    bf16x8 afrag[4];
    load_afrag(afrag, A, m0, M, quad);

    f32x4 acc[8];
#pragma unroll
    for (int nt = 0; nt < 8; nt++) acc[nt] = f32x4{0.f, 0.f, 0.f, 0.f};

#pragma unroll
    for (int nt = 0; nt < 8; nt++) {
        const u16* brow = Bt + (size_t)(nt * 16 + l16) * 128 + quad * 8;
#pragma unroll
        for (int kb = 0; kb < 4; kb++) {
            bf16x8 b = *(const bf16x8*)(brow + kb * 32);
            acc[nt] = __builtin_amdgcn_mfma_f32_16x16x32_bf16(afrag[kb], b, acc[nt], 0, 0, 0);
        }
    }

    int rbase = bx * 64 + wave * 16 + quad * 4;
#pragma unroll
    for (int nt = 0; nt < 8; nt++) {
#pragma unroll
        for (int rr = 0; rr < 4; rr++) {
            int row = rbase + rr;
            if (row < M) {
                float v = acc[nt][rr];
                if (do_relu) v = v > 0.f ? v : 0.f;
                C[(size_t)row * 128 + nt * 16 + l16] = f2bf(v);
            }
        }
    }
}

__global__ __launch_bounds__(256) void gemm128x2(const u16* A0, const u16* Bt0, u16* C0,
                                                 const u16* A1, const u16* Bt1, u16* C1,
                                                 int M, int do_relu) {
    if (blockIdx.y == 0) gemm_core(A0, Bt0, C0, M, do_relu, blockIdx.x, threadIdx.x);
    else                 gemm_core(A1, Bt1, C1, M, do_relu, blockIdx.x, threadIdx.x);
}

// ---------------- fused final: Zl@BtL + Zh@BtH (lam-scaled) ; Xb@BtX ; gate ; @lin_w ----------------

__global__ __launch_bounds__(256) void fused_final(const u16* __restrict__ Zl, const u16* __restrict__ Zh,
                                                   const u16* __restrict__ Xb,
                                                   const u16* __restrict__ BtL, const u16* __restrict__ BtH,
                                                   const u16* __restrict__ BtX,
                                                   const float* __restrict__ mask,
                                                   const float* __restrict__ lam1, const float* __restrict__ lam2,
                                                   const float* __restrict__ lin_w, const float* __restrict__ lin_b,
                                                   float* __restrict__ out, int M) {
    int wave = threadIdx.x >> 6;
    int lane = threadIdx.x & 63;
    int quad = lane >> 4;
    int l16 = lane & 15;
    int m0 = blockIdx.x * 64 + wave * 16 + l16;

    f32x4 acc[8], acc2[8];
#pragma unroll
    for (int nt = 0; nt < 8; nt++) { acc[nt] = f32x4{0.f, 0.f, 0.f, 0.f}; acc2[nt] = f32x4{0.f, 0.f, 0.f, 0.f}; }

    bf16x8 afrag[4];
    // acc = Zl @ (laml*W2L)
    load_afrag(afrag, Zl, m0, M, quad);
#pragma unroll
    for (int nt = 0; nt < 8; nt++) {
        const u16* brow = BtL + (size_t)(nt * 16 + l16) * 128 + quad * 8;
#pragma unroll
        for (int kb = 0; kb < 4; kb++) {
            bf16x8 b = *(const bf16x8*)(brow + kb * 32);
            acc[nt] = __builtin_amdgcn_mfma_f32_16x16x32_bf16(afrag[kb], b, acc[nt], 0, 0, 0);
        }
    }
    // acc += Zh @ (lamh*W2H)
    load_afrag(afrag, Zh, m0, M, quad);
#pragma unroll
    for (int nt = 0; nt < 8; nt++) {
        const u16* brow = BtH + (size_t)(nt * 16 + l16) * 128 + quad * 8;
#pragma unroll
        for (int kb = 0; kb < 4; kb++) {
            bf16x8 b = *(const bf16x8*)(brow + kb * 32);
            acc[nt] = __builtin_amdgcn_mfma_f32_16x16x32_bf16(afrag[kb], b, acc[nt], 0, 0, 0);
        }
    }
    // acc2 = Xb @ WX
    load_afrag(afrag, Xb, m0, M, quad);
#pragma unroll
    for (int nt = 0; nt < 8; nt++) {
        const u16* brow = BtX + (size_t)(nt * 16 + l16) * 128 + quad * 8;
#pragma unroll
        for (int kb = 0; kb < 4; kb++) {
            bf16x8 b = *(const bf16x8*)(brow + kb * 32);
            acc2[nt] = __builtin_amdgcn_mfma_f32_16x16x32_bf16(afrag[kb], b, acc2[nt], 0, 0, 0);
        }
    }

    // gate scalars
    float e0 = __expf(lam1[0]), e1 = __expf(lam1[1]);
    float lamxl = e0 / (e0 + e1);
    float f0 = __expf(lam2[0]), f1 = __expf(lam2[1]);
    float lamxh = f0 / (f0 + f1);

    int rbase = blockIdx.x * 64 + wave * 16 + quad * 4;
    float lamx[4];
#pragma unroll
    for (int rr = 0; rr < 4; rr++) {
        int row = rbase + rr;
        bool mi = (row < M) && (mask[row] != 0.f);
        lamx[rr] = mi ? lamxl : lamxh;
    }

    float part[4][10];
#pragma unroll
    for (int rr = 0; rr < 4; rr++)
#pragma unroll
        for (int c = 0; c < 10; c++) part[rr][c] = 0.f;

#pragma unroll
    for (int nt = 0; nt < 8; nt++) {
        const float* lw = lin_w + (size_t)(nt * 16 + l16) * 10;
        float lwv[10];
#pragma unroll
        for (int c = 0; c < 10; c++) lwv[c] = lw[c];
#pragma unroll
        for (int rr = 0; rr < 4; rr++) {
            float p = lamx[rr] * acc2[nt][rr] + acc[nt][rr];
            p = p > 0.f ? p : 0.f;
#pragma unroll
            for (int c = 0; c < 10; c++) part[rr][c] += p * lwv[c];
        }
    }
#pragma unroll
    for (int rr = 0; rr < 4; rr++)
#pragma unroll
        for (int c = 0; c < 10; c++) {
            part[rr][c] += __shfl_xor(part[rr][c], 1);
            part[rr][c] += __shfl_xor(part[rr][c], 2);
            part[rr][c] += __shfl_xor(part[rr][c], 4);
            part[rr][c] += __shfl_xor(part[rr][c], 8);
        }
    if (l16 == 0) {
#pragma unroll
        for (int rr = 0; rr < 4; rr++) {
            int row = rbase + rr;
            if (row < M) {
#pragma unroll
                for (int c = 0; c < 10; c++)
                    out[(size_t)row * 10 + c] = part[rr][c] + lin_b[c];
            }
        }
    }
}

// ---------------- launch ----------------

extern "C" void kernel_launch(void* const* d_in, const int* in_sizes, int n_in,
                              void* d_out, int out_size, void* d_ws, size_t ws_size,
                              hipStream_t stream) {
    const float* x = (const float*)d_in[0];
    const int* ei = (const int*)d_in[1];
    const float* mask = (const float*)d_in[2];
    const float* W1L = (const float*)d_in[3];
    const float* W1H = (const float*)d_in[4];
    const float* W2L = (const float*)d_in[5];
    const float* W2H = (const float*)d_in[6];
    const float* WX = (const float*)d_in[7];
    const float* lam1 = (const float*)d_in[8];
    const float* lam2 = (const float*)d_in[9];
    const float* lin_w = (const float*)d_in[10];
    const float* lin_b = (const float*)d_in[11];
    float* out = (float*)d_out;

    int E = in_sizes[1] / 2;
    int n = in_sizes[2];

    char* w = (char*)d_ws;
    size_t off = 0;
    auto alloc = [&](size_t bytes) -> void* {
        off = (off + 255) & ~(size_t)255;
        void* p = w + off;
        off += bytes;
        return p;
    };
    int* cnt = (int*)alloc((size_t)2 * n * 4);   // cnt | cntm contiguous for one memset
    int* cntm = cnt + n;
    int* rowptr = (int*)alloc((size_t)(n + 1) * 4);
    int* cursL = (int*)alloc((size_t)n * 4);
    int* cursH = (int*)alloc((size_t)n * 4);
    int* midp = (int*)alloc((size_t)n * 4);
    int* blocksum = (int*)alloc(128 * 4);
    int* blockoff = (int*)alloc(128 * 4);
    int* sorted = (int*)alloc((size_t)E * 4);
    float* dinvL = (float*)alloc((size_t)n * 4);
    float* dinvH = (float*)alloc((size_t)n * 4);
    float* dinvLL = (float*)alloc((size_t)n * 4);
    float* dinvHH = (float*)alloc((size_t)n * 4);
    float2* diag1 = (float2*)alloc((size_t)n * 8);
    float2* diag2 = (float2*)alloc((size_t)n * 8);
    u16* Bt = (u16*)alloc(5 * 16384 * 2);
    size_t actb = (size_t)n * 128 * 2;
    u16* Xb = (u16*)alloc(actb);
    u16* B0 = (u16*)alloc(actb);
    u16* B1 = (u16*)alloc(actb);
    u16* B2 = (u16*)alloc(actb);
    u16* B3 = (u16*)alloc(actb);

    hipMemsetAsync(cnt, 0, (size_t)2 * n * 4, stream);

    int eblk = (E + 255) / 256;
    int nblk256 = (n + 255) / 256;
    int nblkScan = (n + SCAN_B - 1) / SCAN_B;

    cvt_bf16<<<(n * 128 / 4 + 255) / 256, 256, 0, stream>>>(x, Xb, n * 128 / 4);
    edge_stats<<<eblk, 256, 0, stream>>>(ei, mask, cnt, cntm, E);
    scanA<<<nblkScan, 1024, 0, stream>>>(cnt, rowptr, blocksum, n);
    scanB<<<1, 128, 0, stream>>>(blocksum, blockoff, nblkScan, rowptr, n);
    scanC<<<nblk256, 256, 0, stream>>>(rowptr, blockoff, cnt, cntm, mask,
                                       cursL, cursH, midp,
                                       dinvL, dinvH, dinvLL, dinvHH, diag1, diag2, n);
    scatter_edges<<<eblk, 256, 0, stream>>>(ei, mask, cursL, cursH, midp, sorted, E);

    int rowsblk = (n + 3) / 4;
    int gemmblk = (n + 63) / 64;

    // layer 1: dual spmm from x, then two GEMMs with relu (batched)
    spmm1<<<rowsblk, 256, 0, stream>>>(Xb, rowptr, sorted, mask, dinvL, dinvH, diag1, B0, B1, n);
    transposeW<<<320, 256, 0, stream>>>(W1L, W1H, W2L, W2H, WX, lam1, lam2, Bt);
    gemm128x2<<<dim3(gemmblk, 2), 256, 0, stream>>>(B0, Bt + 0 * 16384, B2,
                                                    B1, Bt + 1 * 16384, B3, n, 1);

    // layer 2: dual spmm (partitioned)
    spmm2<<<rowsblk, 256, 0, stream>>>(B2, B3, rowptr, midp, sorted, dinvLL, dinvHH, diag2, B0, B1, n);

    // fused: Zl@(laml*W2L) + Zh@(lamh*W2H), Xb@WX, gate, relu, @lin_w + b
    fused_final<<<gemmblk, 256, 0, stream>>>(B0, B1, Xb,
                                             Bt + 2 * 16384, Bt + 3 * 16384, Bt + 4 * 16384,
                                             mask, lam1, lam2, lin_w, lin_b, out, n);
}

// Round 5
// 529.110 us; speedup vs baseline: 1.8068x; 1.1520x over previous
//
#include <hip/hip_runtime.h>
#include <stdint.h>

typedef unsigned int u32;
typedef unsigned short u16;

#define DI __device__ __forceinline__

DI float bf2f(u16 u) { union { u32 i; float f; } v; v.i = ((u32)u) << 16; return v.f; }
DI u16 f2bf(float f) {
    union { u32 i; float f; } v; v.f = f;
    u32 u = v.i;
    u32 r = (u + 0x7fffu + ((u >> 16) & 1u)) >> 16;
    return (u16)r;
}
DI float2 unpack2(u32 x) { return make_float2(bf2f((u16)(x & 0xffffu)), bf2f((u16)(x >> 16))); }
DI u32 pack2(float a, float b) { return (u32)f2bf(a) | ((u32)f2bf(b) << 16); }

DI void fma8(float* acc, float w, uint4 xv) {
    float2 f0 = unpack2(xv.x), f1 = unpack2(xv.y), f2 = unpack2(xv.z), f3 = unpack2(xv.w);
    acc[0] += w * f0.x; acc[1] += w * f0.y; acc[2] += w * f1.x; acc[3] += w * f1.y;
    acc[4] += w * f2.x; acc[5] += w * f2.y; acc[6] += w * f3.x; acc[7] += w * f3.y;
}

DI uint4 scale8(uint4 v, float s) {
    uint4 r;
    float2 f;
    f = unpack2(v.x); r.x = pack2(f.x * s, f.y * s);
    f = unpack2(v.y); r.y = pack2(f.x * s, f.y * s);
    f = unpack2(v.z); r.z = pack2(f.x * s, f.y * s);
    f = unpack2(v.w); r.w = pack2(f.x * s, f.y * s);
    return r;
}

// ---------------- convert x (f32) -> bf16 ----------------

__global__ void cvt_bf16(const float* __restrict__ X, u16* __restrict__ Xb, int total4) {
    int i = blockIdx.x * blockDim.x + threadIdx.x;
    if (i >= total4) return;
    float4 v = ((const float4*)X)[i];
    ushort4 o;
    o.x = f2bf(v.x); o.y = f2bf(v.y); o.z = f2bf(v.z); o.w = f2bf(v.w);
    ((ushort4*)Xb)[i] = o;
}

// ---------------- CSR build ----------------

__global__ void edge_stats(const int* __restrict__ ei, const float* __restrict__ mask,
                           int* __restrict__ cnt, int* __restrict__ cntm, int E) {
    int e = blockIdx.x * blockDim.x + threadIdx.x;
    if (e >= E) return;
    int c = ei[e];          // src (col)
    int r = ei[E + e];      // dst (row)
    if (r != c) {
        atomicAdd(&cnt[r], 1);
        if (mask[c] != 0.f) atomicAdd(&cntm[r], 1);
    }
}

#define SCAN_B 1024
__global__ __launch_bounds__(1024) void scanA(const int* __restrict__ cnt, int* __restrict__ rowptr,
                                              int* __restrict__ blocksum, int n) {
    __shared__ int s[SCAN_B];
    int t = threadIdx.x;
    int i = blockIdx.x * SCAN_B + t;
    int v = (i < n) ? cnt[i] : 0;
    s[t] = v; __syncthreads();
    for (int off = 1; off < SCAN_B; off <<= 1) {
        int tmp = (t >= off) ? s[t - off] : 0;
        __syncthreads();
        s[t] += tmp;
        __syncthreads();
    }
    if (i < n) rowptr[i] = s[t] - v;   // local exclusive
    if (t == SCAN_B - 1) blocksum[blockIdx.x] = s[t];
}

__global__ void scanB(const int* __restrict__ blocksum, int* __restrict__ blockoff,
                      int nblk, int* __restrict__ rowptr, int n) {
    __shared__ int s[128];
    int t = threadIdx.x;
    int v = (t < nblk) ? blocksum[t] : 0;
    s[t] = v; __syncthreads();
    for (int off = 1; off < 128; off <<= 1) {
        int tmp = (t >= off) ? s[t - off] : 0;
        __syncthreads();
        s[t] += tmp;
        __syncthreads();
    }
    if (t < nblk) blockoff[t] = s[t] - v;
    if (t == 127) rowptr[n] = s[127];
}

// scanC fused with norm
__global__ void scanC(int* __restrict__ rowptr, const int* __restrict__ blockoff,
                      const int* __restrict__ cnt, const int* __restrict__ cntm,
                      const float* __restrict__ mask,
                      int* __restrict__ cursL, int* __restrict__ cursH, int* __restrict__ mid,
                      float* __restrict__ dinvL, float* __restrict__ dinvH,
                      float* __restrict__ dinvLL, float* __restrict__ dinvHH,
                      float2* __restrict__ diag1, float2* __restrict__ diag2, int n) {
    int i = blockIdx.x * blockDim.x + threadIdx.x;
    if (i >= n) return;
    int v = rowptr[i] + blockoff[i >> 10];
    rowptr[i] = v;
    cursL[i] = v;
    cursH[i] = 0;
    float c = (float)cnt[i];
    float cm = (float)cntm[i];
    mid[i] = v + cntm[i];
    bool mi = mask[i] != 0.f;
    float degL = (mi ? c : 0.f) + 1.f;
    float degH = (mi ? 0.f : c) + 1.f;
    float degLL = cm + 1.f;
    float degHH = (c - cm) + 1.f;
    dinvL[i] = rsqrtf(degL);
    dinvH[i] = rsqrtf(degH);
    dinvLL[i] = rsqrtf(degLL);
    dinvHH[i] = rsqrtf(degHH);
    diag1[i] = make_float2(1.f / degL, 1.f / degH);
    diag2[i] = make_float2(1.f / degLL, 1.f / degHH);
}

__global__ void scatter_edges(const int* __restrict__ ei, const float* __restrict__ mask,
                              int* __restrict__ cursL, int* __restrict__ cursH,
                              const int* __restrict__ mid,
                              int* __restrict__ sorted, int E) {
    int e = blockIdx.x * blockDim.x + threadIdx.x;
    if (e >= E) return;
    int c = ei[e];
    int r = ei[E + e];
    if (r != c) {
        int pos;
        if (mask[c] != 0.f) pos = atomicAdd(&cursL[r], 1);
        else                pos = mid[r] + atomicAdd(&cursH[r], 1);
        sorted[pos] = c;
    }
}

// ---------------- SpMM layer 1 ----------------

__global__ __launch_bounds__(256) void spmm1(const u16* __restrict__ X,
                                             const int* __restrict__ rowptr, const int* __restrict__ sorted,
                                             const float* __restrict__ mask,
                                             const float* __restrict__ dinvL, const float* __restrict__ dinvH,
                                             const float2* __restrict__ diag1,
                                             u16* __restrict__ Yl, u16* __restrict__ Yh, int n) {
    int r = blockIdx.x * 4 + (threadIdx.x >> 6);
    if (r >= n) return;
    int lane = threadIdx.x & 63;
    int q = lane >> 4, l16 = lane & 15;
    bool mi = mask[r] != 0.f;
    const float* dinvA = mi ? dinvL : dinvH;
    float da = dinvA[r];
    float2 dg = diag1[r];
    float diag = mi ? dg.x : dg.y;

    const uint4* Xv = (const uint4*)X;
    uint4 xown = Xv[(size_t)r * 16 + l16];

    float acc[8] = {0.f, 0.f, 0.f, 0.f, 0.f, 0.f, 0.f, 0.f};
    int e0 = rowptr[r], e1 = rowptr[r + 1];
    int last = e1 - 1;
    for (int base = e0; base < e1; base += 8) {
        int s0 = base + q, s1 = base + 4 + q;
        int i0 = min(s0, last), i1 = min(s1, last);
        int c0 = sorted[i0], c1 = sorted[i1];
        float w0 = (s0 < e1) ? da * dinvA[c0] : 0.f;
        float w1 = (s1 < e1) ? da * dinvA[c1] : 0.f;
        uint4 x0 = Xv[(size_t)c0 * 16 + l16];
        uint4 x1 = Xv[(size_t)c1 * 16 + l16];
        fma8(acc, w0, x0);
        fma8(acc, w1, x1);
    }
#pragma unroll
    for (int k = 0; k < 8; k++) {
        acc[k] += __shfl_xor(acc[k], 16);
        acc[k] += __shfl_xor(acc[k], 32);
    }
    float2 o0 = unpack2(xown.x), o1 = unpack2(xown.y), o2 = unpack2(xown.z), o3 = unpack2(xown.w);
    uint4 res;
    res.x = pack2(acc[0] + diag * o0.x, acc[1] + diag * o0.y);
    res.y = pack2(acc[2] + diag * o1.x, acc[3] + diag * o1.y);
    res.z = pack2(acc[4] + diag * o2.x, acc[5] + diag * o2.y);
    res.w = pack2(acc[6] + diag * o3.x, acc[7] + diag * o3.y);
    uint4* Ya = (uint4*)(mi ? Yl : Yh);
    uint4* Yc = (uint4*)(mi ? Yh : Yl);
    if (q == 0) Ya[(size_t)r * 16 + l16] = res;
    if (q == 1) Yc[(size_t)r * 16 + l16] = xown;   // deg=1, diag=1 -> exact copy
}

// ---------------- SpMM layer 2: partitioned rows, two uniform phases ----------------

__global__ __launch_bounds__(256) void spmm2(const u16* __restrict__ XL, const u16* __restrict__ XH,
                                             const int* __restrict__ rowptr, const int* __restrict__ mid,
                                             const int* __restrict__ sorted,
                                             const float* __restrict__ dinvLL, const float* __restrict__ dinvHH,
                                             const float2* __restrict__ diag2,
                                             u16* __restrict__ Zl, u16* __restrict__ Zh, int n) {
    int r = blockIdx.x * 4 + (threadIdx.x >> 6);
    if (r >= n) return;
    int lane = threadIdx.x & 63;
    int q = lane >> 4, l16 = lane & 15;

    float dllr = dinvLL[r], dhhr = dinvHH[r];
    float2 dg = diag2[r];

    const uint4* XLv = (const uint4*)XL;
    const uint4* XHv = (const uint4*)XH;
    uint4 xlown = XLv[(size_t)r * 16 + l16];
    uint4 xhown = XHv[(size_t)r * 16 + l16];

    float accL[8] = {0.f, 0.f, 0.f, 0.f, 0.f, 0.f, 0.f, 0.f};
    float accH[8] = {0.f, 0.f, 0.f, 0.f, 0.f, 0.f, 0.f, 0.f};
    int e0 = rowptr[r], m = mid[r], e1 = rowptr[r + 1];

    int lastL = m - 1;
    for (int base = e0; base < m; base += 8) {
        int s0 = base + q, s1 = base + 4 + q;
        int i0 = min(s0, lastL), i1 = min(s1, lastL);
        int c0 = sorted[i0], c1 = sorted[i1];
        float w0 = (s0 < m) ? dllr * dinvLL[c0] : 0.f;
        float w1 = (s1 < m) ? dllr * dinvLL[c1] : 0.f;
        uint4 x0 = XLv[(size_t)c0 * 16 + l16];
        uint4 x1 = XLv[(size_t)c1 * 16 + l16];
        fma8(accL, w0, x0);
        fma8(accL, w1, x1);
    }
    int lastH = e1 - 1;
    for (int base = m; base < e1; base += 8) {
        int s0 = base + q, s1 = base + 4 + q;
        int i0 = min(s0, lastH), i1 = min(s1, lastH);
        int c0 = sorted[i0], c1 = sorted[i1];
        float w0 = (s0 < e1) ? dhhr * dinvHH[c0] : 0.f;
        float w1 = (s1 < e1) ? dhhr * dinvHH[c1] : 0.f;
        uint4 x0 = XHv[(size_t)c0 * 16 + l16];
        uint4 x1 = XHv[(size_t)c1 * 16 + l16];
        fma8(accH, w0, x0);
        fma8(accH, w1, x1);
    }
#pragma unroll
    for (int k = 0; k < 8; k++) {
        accL[k] += __shfl_xor(accL[k], 16);
        accL[k] += __shfl_xor(accL[k], 32);
        accH[k] += __shfl_xor(accH[k], 16);
        accH[k] += __shfl_xor(accH[k], 32);
    }
    float2 l0 = unpack2(xlown.x), l1 = unpack2(xlown.y), l2 = unpack2(xlown.z), l3 = unpack2(xlown.w);
    float2 h0 = unpack2(xhown.x), h1 = unpack2(xhown.y), h2 = unpack2(xhown.z), h3 = unpack2(xhown.w);
    float cl = dg.x, ch = dg.y;
    uint4 rl, rh;
    rl.x = pack2(accL[0] + cl * l0.x, accL[1] + cl * l0.y);
    rl.y = pack2(accL[2] + cl * l1.x, accL[3] + cl * l1.y);
    rl.z = pack2(accL[4] + cl * l2.x, accL[5] + cl * l2.y);
    rl.w = pack2(accL[6] + cl * l3.x, accL[7] + cl * l3.y);
    rh.x = pack2(accH[0] + ch * h0.x, accH[1] + ch * h0.y);
    rh.y = pack2(accH[2] + ch * h1.x, accH[3] + ch * h1.y);
    rh.z = pack2(accH[4] + ch * h2.x, accH[5] + ch * h2.y);
    rh.w = pack2(accH[6] + ch * h3.x, accH[7] + ch * h3.y);
    if (q == 0) ((uint4*)Zl)[(size_t)r * 16 + l16] = rl;
    if (q == 1) ((uint4*)Zh)[(size_t)r * 16 + l16] = rh;
}

// ---------------- weight transpose f32 -> bf16, lam folded into W2L/W2H ----------------

__global__ void transposeW(const float* __restrict__ W1L, const float* __restrict__ W1H,
                           const float* __restrict__ W2L, const float* __restrict__ W2H,
                           const float* __restrict__ WX,
                           const float* __restrict__ lam1, const float* __restrict__ lam2,
                           u16* __restrict__ Bt) {
    int w = blockIdx.x >> 6;                         // which weight
    int idx = (blockIdx.x & 63) * 256 + threadIdx.x; // 0..16383
    float scale = 1.f;
    if (w == 2) { float e0 = __expf(lam1[0]), e1 = __expf(lam1[1]); scale = e1 / (e0 + e1); }
    if (w == 3) { float f0 = __expf(lam2[0]), f1 = __expf(lam2[1]); scale = f1 / (f0 + f1); }
    const float* src = (w == 0) ? W1L : (w == 1) ? W1H : (w == 2) ? W2L : (w == 3) ? W2H : WX;
    int k = idx >> 7, nn = idx & 127;
    Bt[(size_t)w * 16384 + (size_t)nn * 128 + k] = f2bf(scale * src[idx]);
}

// ---------------- LDS-staged MFMA GEMM building blocks ----------------

typedef __attribute__((ext_vector_type(8))) short bf16x8;
typedef __attribute__((ext_vector_type(4))) float f32x4;

// Stage Bt (32 KB, [n][k] bf16) into LDS in MFMA-fragment order:
// frag (nt,kb) occupies 64 consecutive uint4 at (nt*4+kb)*64, indexed by lane.
DI void stageB(const uint4* __restrict__ Bt4, uint4* Bs, int tid) {
#pragma unroll
    for (int i = 0; i < 8; i++) {
        int g = i * 256 + tid;           // coalesced global read
        int nn = g >> 4, c = g & 15;     // c = kb*4+quad
        int d = ((nn >> 4) * 4 + (c >> 2)) * 64 + (c & 3) * 16 + (nn & 15);
        Bs[d] = Bt4[g];
    }
}

DI void loadA(uint4* a, const uint4* __restrict__ A4, int mr, int quad) {
#pragma unroll
    for (int kb = 0; kb < 4; kb++)
        a[kb] = A4[(size_t)mr * 16 + kb * 4 + quad];
}

DI void mfmaSec(const uint4* a, const uint4* Bs, f32x4* acc, int lane) {
#pragma unroll
    for (int nt = 0; nt < 8; nt++)
#pragma unroll
        for (int kb = 0; kb < 4; kb++) {
            bf16x8 av = *(const bf16x8*)&a[kb];
            bf16x8 bv = *(const bf16x8*)&Bs[(nt * 4 + kb) * 64 + lane];
            acc[nt] = __builtin_amdgcn_mfma_f32_16x16x32_bf16(av, bv, acc[nt], 0, 0, 0);
        }
}

// ---------------- layer-1 GEMM (2 jobs via blockIdx.y), relu, coalesced store ----------------

__global__ __launch_bounds__(256) void gemm_lds(const u16* __restrict__ A0, const u16* __restrict__ Bt0,
                                                u16* __restrict__ C0,
                                                const u16* __restrict__ A1, const u16* __restrict__ Bt1,
                                                u16* __restrict__ C1, int M) {
    __shared__ uint4 Bs[2048];   // 32 KB; reused as C bounce (needs 1024)
    const u16* A = blockIdx.y ? A1 : A0;
    const u16* Bt = blockIdx.y ? Bt1 : Bt0;
    u16* C = blockIdx.y ? C1 : C0;

    int tid = threadIdx.x;
    int wave = tid >> 6, lane = tid & 63, quad = lane >> 4, l16 = lane & 15;
    int tile = blockIdx.x * 64;
    int m0 = tile + wave * 16 + l16;
    int mr = min(m0, M - 1);

    uint4 a[4];
    loadA(a, (const uint4*)A, mr, quad);     // issued before staging: latency hidden
    stageB((const uint4*)Bt, Bs, tid);
    __syncthreads();

    f32x4 acc[8];
#pragma unroll
    for (int nt = 0; nt < 8; nt++) acc[nt] = f32x4{0.f, 0.f, 0.f, 0.f};
    mfmaSec(a, Bs, acc, lane);

    __syncthreads();                          // Bs reads done; reuse as C bounce
    u16* Cs = (u16*)Bs;
    int lrow0 = wave * 16 + quad * 4;
#pragma unroll
    for (int nt = 0; nt < 8; nt++)
#pragma unroll
        for (int rr = 0; rr < 4; rr++) {
            float v = acc[nt][rr];
            v = v > 0.f ? v : 0.f;            // relu (layer 1 only)
            Cs[(lrow0 + rr) * 128 + nt * 16 + l16] = f2bf(v);
        }
    __syncthreads();
    uint4* Cs4 = (uint4*)Bs;
    uint4* C4 = (uint4*)C;
#pragma unroll
    for (int i = 0; i < 4; i++) {
        int g = i * 256 + tid;                // 1024 uint4 = 64 rows
        int grow = tile + (g >> 4);
        if (grow < M) C4[(size_t)grow * 16 + (g & 15)] = Cs4[g];
    }
}

// ---------------- fused final: relu(Zl@BtL' + Zh@BtH' + lamx*Xb@BtX) @ lin_w + b ----------------

__global__ __launch_bounds__(256) void fused_final(const u16* __restrict__ Zl, const u16* __restrict__ Zh,
                                                   const u16* __restrict__ Xb,
                                                   const u16* __restrict__ BtL, const u16* __restrict__ BtH,
                                                   const u16* __restrict__ BtX,
                                                   const float* __restrict__ mask,
                                                   const float* __restrict__ lam1, const float* __restrict__ lam2,
                                                   const float* __restrict__ lin_w, const float* __restrict__ lin_b,
                                                   float* __restrict__ out, int M) {
    __shared__ uint4 Bs[2048];    // 32 KB, restaged per section
    __shared__ float lws[1280];   // lin_w 128x10 f32

    int tid = threadIdx.x;
    int wave = tid >> 6, lane = tid & 63, quad = lane >> 4, l16 = lane & 15;
    int tile = blockIdx.x * 64;
    int m0 = tile + wave * 16 + l16;
    int mr = min(m0, M - 1);

    // section-0 A (Zl) + lin_w staging + section-0 B staging
    uint4 a[4], an[4];
    loadA(a, (const uint4*)Zl, mr, quad);
    {
        const uint4* lw4 = (const uint4*)lin_w;
        uint4* lws4 = (uint4*)lws;
        lws4[tid] = lw4[tid];
        if (tid < 64) lws4[256 + tid] = lw4[256 + tid];
    }
    stageB((const uint4*)BtL, Bs, tid);

    // gate scalar for this lane's row (X-section pre-scale)
    float e0 = __expf(lam1[0]), e1 = __expf(lam1[1]);
    float lamxl = e0 / (e0 + e1);
    float f0 = __expf(lam2[0]), f1 = __expf(lam2[1]);
    float lamxh = f0 / (f0 + f1);
    float lamx = (mask[mr] != 0.f) ? lamxl : lamxh;

    __syncthreads();

    f32x4 acc[8];
#pragma unroll
    for (int nt = 0; nt < 8; nt++) acc[nt] = f32x4{0.f, 0.f, 0.f, 0.f};

    loadA(an, (const uint4*)Zh, mr, quad);    // prefetch section-1 A
    mfmaSec(a, Bs, acc, lane);                // section 0

    __syncthreads();
    stageB((const uint4*)BtH, Bs, tid);
#pragma unroll
    for (int kb = 0; kb < 4; kb++) a[kb] = an[kb];
    loadA(an, (const uint4*)Xb, mr, quad);    // prefetch section-2 A
    __syncthreads();
    mfmaSec(a, Bs, acc, lane);                // section 1

    __syncthreads();
    stageB((const uint4*)BtX, Bs, tid);
#pragma unroll
    for (int kb = 0; kb < 4; kb++) a[kb] = scale8(an[kb], lamx);   // fold per-row gate into A
    __syncthreads();
    mfmaSec(a, Bs, acc, lane);                // section 2

    // epilogue: relu + 128->10 projection (lin_w from LDS), shuffle-reduce over l16
    int rbase = tile + wave * 16 + quad * 4;
    float part[4][10];
#pragma unroll
    for (int rr = 0; rr < 4; rr++)
#pragma unroll
        for (int c = 0; c < 10; c++) part[rr][c] = 0.f;

#pragma unroll
    for (int nt = 0; nt < 8; nt++) {
        const float* lw = lws + (nt * 16 + l16) * 10;
        float lwv[10];
#pragma unroll
        for (int c = 0; c < 10; c++) lwv[c] = lw[c];
#pragma unroll
        for (int rr = 0; rr < 4; rr++) {
            float p = acc[nt][rr];
            p = p > 0.f ? p : 0.f;
#pragma unroll
            for (int c = 0; c < 10; c++) part[rr][c] += p * lwv[c];
        }
    }
#pragma unroll
    for (int rr = 0; rr < 4; rr++)
#pragma unroll
        for (int c = 0; c < 10; c++) {
            part[rr][c] += __shfl_xor(part[rr][c], 1);
            part[rr][c] += __shfl_xor(part[rr][c], 2);
            part[rr][c] += __shfl_xor(part[rr][c], 4);
            part[rr][c] += __shfl_xor(part[rr][c], 8);
        }
    if (l16 == 0) {
#pragma unroll
        for (int rr = 0; rr < 4; rr++) {
            int row = rbase + rr;
            if (row < M) {
#pragma unroll
                for (int c = 0; c < 10; c++)
                    out[(size_t)row * 10 + c] = part[rr][c] + lin_b[c];
            }
        }
    }
}

// ---------------- launch ----------------

extern "C" void kernel_launch(void* const* d_in, const int* in_sizes, int n_in,
                              void* d_out, int out_size, void* d_ws, size_t ws_size,
                              hipStream_t stream) {
    const float* x = (const float*)d_in[0];
    const int* ei = (const int*)d_in[1];
    const float* mask = (const float*)d_in[2];
    const float* W1L = (const float*)d_in[3];
    const float* W1H = (const float*)d_in[4];
    const float* W2L = (const float*)d_in[5];
    const float* W2H = (const float*)d_in[6];
    const float* WX = (const float*)d_in[7];
    const float* lam1 = (const float*)d_in[8];
    const float* lam2 = (const float*)d_in[9];
    const float* lin_w = (const float*)d_in[10];
    const float* lin_b = (const float*)d_in[11];
    float* out = (float*)d_out;

    int E = in_sizes[1] / 2;
    int n = in_sizes[2];

    char* w = (char*)d_ws;
    size_t off = 0;
    auto alloc = [&](size_t bytes) -> void* {
        off = (off + 255) & ~(size_t)255;
        void* p = w + off;
        off += bytes;
        return p;
    };
    int* cnt = (int*)alloc((size_t)2 * n * 4);   // cnt | cntm contiguous for one memset
    int* cntm = cnt + n;
    int* rowptr = (int*)alloc((size_t)(n + 1) * 4);
    int* cursL = (int*)alloc((size_t)n * 4);
    int* cursH = (int*)alloc((size_t)n * 4);
    int* midp = (int*)alloc((size_t)n * 4);
    int* blocksum = (int*)alloc(128 * 4);
    int* blockoff = (int*)alloc(128 * 4);
    int* sorted = (int*)alloc((size_t)E * 4);
    float* dinvL = (float*)alloc((size_t)n * 4);
    float* dinvH = (float*)alloc((size_t)n * 4);
    float* dinvLL = (float*)alloc((size_t)n * 4);
    float* dinvHH = (float*)alloc((size_t)n * 4);
    float2* diag1 = (float2*)alloc((size_t)n * 8);
    float2* diag2 = (float2*)alloc((size_t)n * 8);
    u16* Bt = (u16*)alloc(5 * 16384 * 2);
    size_t actb = (size_t)n * 128 * 2;
    u16* Xb = (u16*)alloc(actb);
    u16* B0 = (u16*)alloc(actb);
    u16* B1 = (u16*)alloc(actb);
    u16* B2 = (u16*)alloc(actb);
    u16* B3 = (u16*)alloc(actb);

    hipMemsetAsync(cnt, 0, (size_t)2 * n * 4, stream);

    int eblk = (E + 255) / 256;
    int nblk256 = (n + 255) / 256;
    int nblkScan = (n + SCAN_B - 1) / SCAN_B;

    cvt_bf16<<<(n * 128 / 4 + 255) / 256, 256, 0, stream>>>(x, Xb, n * 128 / 4);
    edge_stats<<<eblk, 256, 0, stream>>>(ei, mask, cnt, cntm, E);
    scanA<<<nblkScan, 1024, 0, stream>>>(cnt, rowptr, blocksum, n);
    scanB<<<1, 128, 0, stream>>>(blocksum, blockoff, nblkScan, rowptr, n);
    scanC<<<nblk256, 256, 0, stream>>>(rowptr, blockoff, cnt, cntm, mask,
                                       cursL, cursH, midp,
                                       dinvL, dinvH, dinvLL, dinvHH, diag1, diag2, n);
    scatter_edges<<<eblk, 256, 0, stream>>>(ei, mask, cursL, cursH, midp, sorted, E);

    int rowsblk = (n + 3) / 4;
    int gemmblk = (n + 63) / 64;

    // layer 1: dual spmm from x, then two GEMMs with relu (LDS-staged, 2 jobs)
    spmm1<<<rowsblk, 256, 0, stream>>>(Xb, rowptr, sorted, mask, dinvL, dinvH, diag1, B0, B1, n);
    transposeW<<<320, 256, 0, stream>>>(W1L, W1H, W2L, W2H, WX, lam1, lam2, Bt);
    gemm_lds<<<dim3(gemmblk, 2), 256, 0, stream>>>(B0, Bt + 0 * 16384, B2,
                                                   B1, Bt + 1 * 16384, B3, n);

    // layer 2: dual spmm (partitioned)
    spmm2<<<rowsblk, 256, 0, stream>>>(B2, B3, rowptr, midp, sorted, dinvLL, dinvHH, diag2, B0, B1, n);

    // fused: relu(Zl@(laml*W2L) + Zh@(lamh*W2H) + lamx*Xb@WX) @ lin_w + b
    fused_final<<<gemmblk, 256, 0, stream>>>(B0, B1, Xb,
                                             Bt + 2 * 16384, Bt + 3 * 16384, Bt + 4 * 16384,
                                             mask, lam1, lam2, lin_w, lin_b, out, n);
}